// Round 2
// baseline (429.023 us; speedup 1.0000x reference)
//
#include <hip/hip_runtime.h>
#include <hip/hip_bf16.h>

#define N_ROI 262144
#define FDIM  256
#define HDIM  64
#define NNET  128

#define CHUNK  32                  // ROIs per chunk (1 MFMA K-tile)
#define NCHUNK 16                  // chunks per block
#define RPB    (CHUNK * NCHUNK)    // 512 ROIs per block
#define NBLK   (N_ROI / RPB)       // 512 blocks -> 2 per CU
#define XPITCH 264                 // shorts per row (256 data + pad)

typedef __attribute__((ext_vector_type(8))) __bf16 bf16x8;
typedef __attribute__((ext_vector_type(8))) short short8;
typedef __attribute__((ext_vector_type(4))) float floatx4;

union frag_cast { short8 s; bf16x8 b; };

#define NEG_INF (-__builtin_huge_valf())

// monotonic float -> uint key (order-preserving), for atomicMax segment max
__device__ __forceinline__ unsigned fkey(float f) {
  unsigned u = __float_as_uint(f);
  return (u & 0x80000000u) ? ~u : (u | 0x80000000u);
}
__device__ __forceinline__ float fkey_inv(unsigned k) {
  unsigned u = (k & 0x80000000u) ? (k ^ 0x80000000u) : ~k;
  return __uint_as_float(u);
}
__device__ __forceinline__ unsigned short f2bf(float f) {  // RNE f32->bf16
  unsigned u = __float_as_uint(f);
  u += 0x7FFFu + ((u >> 16) & 1u);
  return (unsigned short)(u >> 16);
}
__device__ __forceinline__ float bf2f(unsigned short h) {
  return __uint_as_float(((unsigned)h) << 16);
}
// hardware packed cvt (v_cvt_pk_bf16_f32), RNE — hot staging path
__device__ __forceinline__ unsigned cvt2(float a, float b) {
  union { __hip_bfloat162 h; unsigned u; } cv;
  cv.h = __float22bfloat162_rn(make_float2(a, b));
  return cv.u;
}
// swizzled short-index into the x tile. XOR of short-index bits 4,5 with
// (row>>3)&3: makes the scatter transpose read (fixed col, rows quad*8+j)
// conflict-free (each quad -> its own bank octet) while preserving 8-short
// contiguity for ds_read_b128 and 4-short contiguity for staging writes.
__device__ __forceinline__ int sidx(int row, int s) {
  return row * XPITCH + (s ^ (((row >> 3) & 3) << 4));
}

// ---------------- Fused kernel: scores + online-softmax + scatter-GEMM -----
// 512 blocks x 256 thr (2 blocks/CU). Per 32-ROI chunk:
//   stage x (bf16 LDS, swizzled) -> score MFMA (hidden split across waves)
//   -> per-group chunk max -> online rescale of register acc
//   -> w = exp(s - m), masked scatter MFMA  num[g][d] += w * x
// Block emits private (num_b[128][256], den_b[128], m_b[128]) — no atomics.
__global__ __launch_bounds__(256, 2) void fused_kernel(
    const float* __restrict__ x, const int* __restrict__ group,
    const float* __restrict__ W1, const float* __restrict__ b1,
    const float* __restrict__ W2,
    float* __restrict__ num_ws,   // [NBLK][128][257]  (d=256 -> denom)
    float* __restrict__ m_ws)     // [NBLK][128]
{
  __shared__ unsigned short w1t[HDIM][XPITCH];              // W1^T bf16
  __shared__ __align__(16) unsigned short xl[CHUNK * XPITCH];
  __shared__ float scpart[4][CHUNK];
  __shared__ float sc[CHUNK];
  __shared__ int   ggrp[RPB];
  __shared__ unsigned gw[CHUNK];      // (g<<16) | bf16(w)
  __shared__ unsigned tmax[NNET];
  __shared__ __align__(16) float fl[NNET];   // per-chunk rescale factor
  __shared__ float mrun[NNET], dent[NNET], denrun[NNET];

  const int tid  = threadIdx.x;
  const int wave = tid >> 6, lane = tid & 63;
  const int col  = lane & 15, quad = lane >> 4;

  // stage W1^T bf16 once (cold)
  {
    const int n = tid & 63, kg = tid >> 6;          // kg 0..3
    for (int p = 0; p < 8; ++p) {
      const int k0 = p * 32 + kg * 8;
      unsigned short tmp[8];
#pragma unroll
      for (int j = 0; j < 8; ++j) tmp[j] = f2bf(W1[(k0 + j) * HDIM + n]);
      *(short8*)&w1t[n][k0] = *(short8*)tmp;
    }
  }
  if (tid < NNET) { mrun[tid] = NEG_INF; denrun[tid] = 0.f; }

  const size_t rbase = (size_t)blockIdx.x * RPB;
  ggrp[tid]       = group[rbase + tid];
  ggrp[tid + 256] = group[rbase + tid + 256];

  const float b1s = b1[wave * 16 + col];    // this wave owns hidden [w*16,w*16+16)
  const float w2s = W2[wave * 16 + col];

  floatx4 acc[8][4];        // scatter acc: 128 groups x 64 dims (this wave)
#pragma unroll
  for (int mt = 0; mt < 8; ++mt)
#pragma unroll
    for (int nt = 0; nt < 4; ++nt) acc[mt][nt] = (floatx4)0.f;

  const float* xb = x + rbase * FDIM;

  // register prefetch: 8 float4 / thread = one 32-ROI chunk (32 KB / block)
  float4 pf[8];
#pragma unroll
  for (int i = 0; i < 8; ++i)
    pf[i] = *(const float4*)(xb + i * 1024 + tid * 4);

  for (int ch = 0; ch < NCHUNK; ++ch) {
    __syncthreads();                 // A: prev scatter done reading xl
    // ---- stage x chunk: row = i*4+wave, dims lane*4..+3 (swizzled)
#pragma unroll
    for (int i = 0; i < 8; ++i) {
      const int row = i * 4 + wave;
      uint2 pk; pk.x = cvt2(pf[i].x, pf[i].y); pk.y = cvt2(pf[i].z, pf[i].w);
      *(uint2*)&xl[sidx(row, lane * 4)] = pk;
    }
    if (tid < NNET) tmax[tid] = 0u;
    __syncthreads();                 // B: xl / tmax ready

    if (ch < NCHUNK - 1) {           // issue next chunk's loads; land under compute
      const float* xn = xb + (size_t)(ch + 1) * CHUNK * FDIM;
#pragma unroll
      for (int i = 0; i < 8; ++i)
        pf[i] = *(const float4*)(xn + i * 1024 + tid * 4);
    }

    // ---- score: wave computes hidden slice [wave*16,+16) for all 32 rows
    floatx4 accS[2];
    accS[0] = (floatx4)0.f; accS[1] = (floatx4)0.f;
#pragma unroll
    for (int c = 0; c < 8; ++c) {
      frag_cast bw;
      bw.s = *(const short8*)&w1t[wave * 16 + col][c * 32 + quad * 8];
#pragma unroll
      for (int mt = 0; mt < 2; ++mt) {
        frag_cast af;
        af.s = *(const short8*)&xl[sidx(mt * 16 + col, c * 32 + quad * 8)];
        accS[mt] = __builtin_amdgcn_mfma_f32_16x16x32_bf16(af.b, bw.b, accS[mt], 0, 0, 0);
      }
    }
#pragma unroll
    for (int mt = 0; mt < 2; ++mt) {   // relu + dot W2 slice, reduce 16 cols
      float pr[4];
#pragma unroll
      for (int r = 0; r < 4; ++r) pr[r] = fmaxf(accS[mt][r] + b1s, 0.f) * w2s;
#pragma unroll
      for (int off = 1; off < 16; off <<= 1)
#pragma unroll
        for (int r = 0; r < 4; ++r) pr[r] += __shfl_xor(pr[r], off, 16);
      if (col == 0) {
#pragma unroll
        for (int r = 0; r < 4; ++r) scpart[wave][mt * 16 + quad * 4 + r] = pr[r];
      }
    }
    __syncthreads();                 // C: scpart ready
    if (tid < CHUNK) {               // combine hidden slices -> score, chunk max
      const float s = scpart[0][tid] + scpart[1][tid] + scpart[2][tid] + scpart[3][tid];
      sc[tid] = s;
      atomicMax(&tmax[ggrp[ch * CHUNK + tid]], fkey(s));
    }
    __syncthreads();                 // D: sc / tmax ready
    if (tid < NNET) {                // online max update per group
      const unsigned tk = tmax[tid];
      float f = 1.f;
      if (tk) {
        const float mo = mrun[tid];
        const float mn = fmaxf(mo, fkey_inv(tk));
        f = __expf(mo - mn);         // mo == -inf -> 0
        mrun[tid] = mn;
      }
      fl[tid] = f;
      dent[tid] = 0.f;
    }
    __syncthreads();                 // E: fl / mrun / dent ready
    if (tid < CHUNK) {
      const int g = ggrp[ch * CHUNK + tid];
      const float w = __expf(sc[tid] - mrun[g]);   // w in (0, 1]
      const unsigned short wb = f2bf(w);
      gw[tid] = ((unsigned)g << 16) | wb;
      atomicAdd(&dent[g], bf2f(wb)); // denom uses the SAME rounded weights as num
    }
    // rescale register accumulators (rows = groups)
#pragma unroll
    for (int mt = 0; mt < 8; ++mt) {
      const floatx4 f4 = *(const floatx4*)&fl[mt * 16 + quad * 4];
#pragma unroll
      for (int nt = 0; nt < 4; ++nt)
#pragma unroll
        for (int r = 0; r < 4; ++r) acc[mt][nt][r] *= f4[r];
    }
    __syncthreads();                 // F: gw / dent ready

    // ---- scatter: wave owns dims [wave*64, +64); K = 32 ROIs (one MFMA K)
    unsigned gwv[8];
#pragma unroll
    for (int j = 0; j < 8; ++j) gwv[j] = gw[quad * 8 + j];
    frag_cast bfx[4];
#pragma unroll
    for (int nt = 0; nt < 4; ++nt) {
      unsigned short bb[8];
#pragma unroll
      for (int j = 0; j < 8; ++j)
        bb[j] = xl[sidx(quad * 8 + j, wave * 64 + nt * 16 + col)];  // conflict-free
      bfx[nt].s = *(short8*)bb;
    }
#pragma unroll
    for (int mt = 0; mt < 8; ++mt) {
      const unsigned gt = (unsigned)(mt * 16 + col);
      unsigned short aa[8];
#pragma unroll
      for (int j = 0; j < 8; ++j)
        aa[j] = ((gwv[j] >> 16) == gt) ? (unsigned short)gwv[j] : (unsigned short)0;
      frag_cast af; af.s = *(short8*)aa;
#pragma unroll
      for (int nt = 0; nt < 4; ++nt)
        acc[mt][nt] = __builtin_amdgcn_mfma_f32_16x16x32_bf16(af.b, bfx[nt].b, acc[mt][nt], 0, 0, 0);
    }
    if (tid < NNET) denrun[tid] = denrun[tid] * fl[tid] + dent[tid];
  }

  // ---- store per-block partials (plain stores, private slice, no atomics)
  float* slice = num_ws + (size_t)blockIdx.x * (NNET * 257);
#pragma unroll
  for (int mt = 0; mt < 8; ++mt)
#pragma unroll
    for (int nt = 0; nt < 4; ++nt)
#pragma unroll
      for (int r = 0; r < 4; ++r)
        slice[(mt * 16 + quad * 4 + r) * 257 + wave * 64 + nt * 16 + col] = acc[mt][nt][r];
  if (tid < NNET) {
    slice[tid * 257 + 256] = denrun[tid];
    m_ws[(size_t)blockIdx.x * NNET + tid] = mrun[tid];
  }
}

// ---------------- Finalize: global max per group + rescaled reduction ------
// 256 blocks: block handles (g = bid>>1, d in [ (bid&1)*128, +128 )).
__global__ __launch_bounds__(256) void finalize_kernel(
    const float* __restrict__ num_ws, const float* __restrict__ m_ws,
    float* __restrict__ out)
{
  const int g     = blockIdx.x >> 1;
  const int dbase = (blockIdx.x & 1) << 7;
  const int tid   = threadIdx.x;
  __shared__ float e_l[NBLK];
  __shared__ float red[8];
  __shared__ float npart[2][128];

  // phase 1: global max over the 512 block maxima, denom sum
  const float m0 = m_ws[(size_t)tid * NNET + g];
  const float m1 = m_ws[(size_t)(tid + 256) * NNET + g];
  float M = fmaxf(m0, m1);
#pragma unroll
  for (int off = 1; off < 64; off <<= 1) M = fmaxf(M, __shfl_xor(M, off));
  if ((tid & 63) == 0) red[tid >> 6] = M;
  __syncthreads();
  M = fmaxf(fmaxf(red[0], red[1]), fmaxf(red[2], red[3]));

  const float e0 = (m0 == NEG_INF) ? 0.f : __expf(m0 - M);
  const float e1 = (m1 == NEG_INF) ? 0.f : __expf(m1 - M);
  e_l[tid]       = e0;
  e_l[tid + 256] = e1;
  float dp = num_ws[(size_t)tid * (NNET * 257) + g * 257 + 256] * e0
           + num_ws[(size_t)(tid + 256) * (NNET * 257) + g * 257 + 256] * e1;
#pragma unroll
  for (int off = 1; off < 64; off <<= 1) dp += __shfl_xor(dp, off);
  if ((tid & 63) == 0) red[4 + (tid >> 6)] = dp;
  __syncthreads();
  const float den = red[4] + red[5] + red[6] + red[7];

  // phase 2: num reduction, b-range split across thread halves (coalesced in d)
  const int dd = tid & 127, half = tid >> 7;
  float nsum = 0.f;
  const float* base = num_ws + (size_t)half * 256 * (NNET * 257) + g * 257 + dbase + dd;
  const float* el   = e_l + half * 256;
#pragma unroll 4
  for (int b = 0; b < 256; ++b)
    nsum += base[(size_t)b * (NNET * 257)] * el[b];
  npart[half][dd] = nsum;
  __syncthreads();
  if (tid < 128) {
    const float num = npart[0][tid] + npart[1][tid];
    out[g * FDIM + dbase + tid] = (den > 0.f) ? num / fmaxf(den, 1e-30f) : 0.f;
  }
}

extern "C" void kernel_launch(void* const* d_in, const int* in_sizes, int n_in,
                              void* d_out, int out_size, void* d_ws, size_t ws_size,
                              hipStream_t stream)
{
  const float* x     = (const float*)d_in[0];
  const int*   group = (const int*)d_in[1];
  const float* W1    = (const float*)d_in[2];
  const float* b1    = (const float*)d_in[3];
  const float* W2    = (const float*)d_in[4];
  // d_in[5] = b2: cancels exactly in exp(score-max)/sum -> unused
  float* out = (float*)d_out;

  // workspace: num[NBLK][128][257] | m[NBLK][128] — fully overwritten, no memset
  float* num_ws = (float*)d_ws;
  float* m_ws   = num_ws + (size_t)NBLK * NNET * 257;

  fused_kernel<<<NBLK, 256, 0, stream>>>(x, group, W1, b1, W2, num_ws, m_ws);
  finalize_kernel<<<2 * NNET, 256, 0, stream>>>(num_ws, m_ws, out);

  (void)in_sizes; (void)n_in; (void)out_size; (void)ws_size;
}